// Round 1
// baseline (718.657 us; speedup 1.0000x reference)
//
#include <hip/hip_runtime.h>
#include <cstdint>

#define Nn 50000
#define Dd 64
#define Ee 800000
#define NBLK 196          // ceil(Nn/256)
#define FC_BLOCKS 512
#define ND4 (Nn*Dd/4)     // 800000 float4s

__device__ __forceinline__ float relu_f(float v){ return v > 0.f ? v : 0.f; }

// ---- degree histogram (self-loops added later as +1) ----
__global__ __launch_bounds__(256) void k_degree(const int* __restrict__ src, const int* __restrict__ dst,
                                                unsigned* __restrict__ dout, unsigned* __restrict__ din){
    int e = blockIdx.x * 256 + threadIdx.x;
    if (e < Ee){
        atomicAdd(&dout[src[e]], 1u);
        atomicAdd(&din[dst[e]], 1u);
    }
}

__global__ __launch_bounds__(256) void k_norms(const unsigned* __restrict__ dout, const unsigned* __restrict__ din,
                                               float* __restrict__ ns, float* __restrict__ nd){
    int i = blockIdx.x * 256 + threadIdx.x;
    if (i < Nn){
        ns[i] = rsqrtf((float)(dout[i] + 1u));   // +1 = self loop
        nd[i] = rsqrtf((float)(din[i] + 1u));
    }
}

// ---- two-level exclusive scan of deg_in -> CSR offsets ----
__global__ __launch_bounds__(256) void k_blocksum(const unsigned* __restrict__ din, unsigned* __restrict__ bsum){
    __shared__ unsigned s[256];
    int t = threadIdx.x; int i = blockIdx.x * 256 + t;
    s[t] = (i < Nn) ? din[i] : 0u;
    __syncthreads();
    for (int off = 128; off > 0; off >>= 1){ if (t < off) s[t] += s[t + off]; __syncthreads(); }
    if (t == 0) bsum[blockIdx.x] = s[0];
}

__global__ __launch_bounds__(256) void k_scanblocks(const unsigned* __restrict__ bsum, unsigned* __restrict__ boff,
                                                    unsigned* __restrict__ offsets){
    __shared__ unsigned s[256];
    int t = threadIdx.x;
    unsigned v = (t < NBLK) ? bsum[t] : 0u;
    s[t] = v; __syncthreads();
    for (int off = 1; off < 256; off <<= 1){
        unsigned add = (t >= off) ? s[t - off] : 0u;
        __syncthreads();
        s[t] += add;
        __syncthreads();
    }
    boff[t] = s[t] - v;                       // exclusive prefix of block sums
    if (t == 255) offsets[Nn] = s[255];       // total == Ee
}

__global__ __launch_bounds__(256) void k_offsets(const unsigned* __restrict__ din, const unsigned* __restrict__ boff,
                                                 unsigned* __restrict__ offsets, unsigned* __restrict__ cursor){
    __shared__ unsigned s[256];
    int t = threadIdx.x; int i = blockIdx.x * 256 + t;
    unsigned v = (i < Nn) ? din[i] : 0u;
    s[t] = v; __syncthreads();
    for (int off = 1; off < 256; off <<= 1){
        unsigned add = (t >= off) ? s[t - off] : 0u;
        __syncthreads();
        s[t] += add;
        __syncthreads();
    }
    if (i < Nn){
        unsigned val = s[t] - v + boff[blockIdx.x];
        offsets[i] = val;
        cursor[i]  = val;
    }
}

__global__ __launch_bounds__(256) void k_fillcsr(const int* __restrict__ src, const int* __restrict__ dst,
                                                 unsigned* __restrict__ cursor, unsigned* __restrict__ csr){
    int e = blockIdx.x * 256 + threadIdx.x;
    if (e < Ee){
        unsigned pos = atomicAdd(&cursor[dst[e]], 1u);
        csr[pos] = (unsigned)src[e];
    }
}

// ---- h = x * norm_src (float4) ----
__global__ __launch_bounds__(256) void k_h(const float* __restrict__ x, const float* __restrict__ ns,
                                           float* __restrict__ h){
    int i = blockIdx.x * 256 + threadIdx.x;   // exactly ND4 threads
    const float4* x4 = (const float4*)x;
    float4* h4 = (float4*)h;
    float s = ns[i >> 4];
    float4 v = x4[i];
    v.x *= s; v.y *= s; v.z *= s; v.w *= s;
    h4[i] = v;
}

// ---- SpMM gather: one wave per node, lane = feature ----
__global__ __launch_bounds__(256) void k_gather(const float* __restrict__ h, const unsigned* __restrict__ offsets,
                                                const unsigned* __restrict__ csr, const float* __restrict__ nd,
                                                float* __restrict__ agg){
    int v = blockIdx.x * 4 + (threadIdx.x >> 6);   // 12500 blocks * 4 waves = 50000 nodes
    int lane = threadIdx.x & 63;
    float acc = h[v * 64 + lane];                  // self loop
    unsigned beg = offsets[v], end = offsets[v + 1];
    for (unsigned e = beg; e < end; ++e){
        int s = (int)csr[e];                       // wave-uniform load
        acc += h[s * 64 + lane];                   // coalesced 256B row
    }
    agg[v * 64 + lane] = acc * nd[v];
}

// ---- x = relu(agg @ W + b): 64-node tile, 4x4 register blocking ----
__global__ __launch_bounds__(256) void k_gemm(const float* __restrict__ agg, const float* __restrict__ W,
                                              const float* __restrict__ bias, float* __restrict__ xout){
    __shared__ float As[64 * 65];   // row-major, pad 65 -> conflict-free column reads
    __shared__ float Ws[64 * 64];   // W[k][n]
    int t = threadIdx.x;
    int m_base = blockIdx.x * 64;
    const float4* W4   = (const float4*)W;
    float4* Ws4        = (float4*)Ws;
    const float4* agg4 = (const float4*)agg;
    #pragma unroll
    for (int i = 0; i < 4; i++){
        int g = t + 256 * i;              // 1024 float4s
        Ws4[g] = W4[g];
        int m = g >> 4, q = g & 15;
        int node = m_base + m;
        float4 v = make_float4(0.f, 0.f, 0.f, 0.f);
        if (node < Nn) v = agg4[node * 16 + q];
        float* dp = &As[m * 65 + q * 4];
        dp[0] = v.x; dp[1] = v.y; dp[2] = v.z; dp[3] = v.w;
    }
    __syncthreads();
    int tm = t >> 4, tn = t & 15;
    float acc[4][4];
    #pragma unroll
    for (int i = 0; i < 4; i++)
        #pragma unroll
        for (int j = 0; j < 4; j++) acc[i][j] = 0.f;
    #pragma unroll 4
    for (int k = 0; k < 64; k++){
        float4 w = *(const float4*)&Ws[k * 64 + tn * 4];
        float a[4];
        #pragma unroll
        for (int i = 0; i < 4; i++) a[i] = As[(tm * 4 + i) * 65 + k];
        #pragma unroll
        for (int i = 0; i < 4; i++){
            acc[i][0] += a[i] * w.x;
            acc[i][1] += a[i] * w.y;
            acc[i][2] += a[i] * w.z;
            acc[i][3] += a[i] * w.w;
        }
    }
    float4 b4 = ((const float4*)bias)[tn];
    float4* x4 = (float4*)xout;
    #pragma unroll
    for (int i = 0; i < 4; i++){
        int node = m_base + tm * 4 + i;
        if (node < Nn){
            float4 r;
            r.x = relu_f(acc[i][0] + b4.x);
            r.y = relu_f(acc[i][1] + b4.y);
            r.z = relu_f(acc[i][2] + b4.z);
            r.w = relu_f(acc[i][3] + b4.w);
            x4[node * 16 + tn] = r;
        }
    }
}

// ---- fc: out[o] = fc_b[o] + sum_i fc_w[o][i]*x[i], 16 partials per thread ----
__global__ __launch_bounds__(256) void k_fc(const float* __restrict__ fcw, const float* __restrict__ x,
                                            float* __restrict__ partials){
    int t = threadIdx.x;
    const float4* x4 = (const float4*)x;
    const float4* w4 = (const float4*)fcw;
    float p[16];
    #pragma unroll
    for (int o = 0; o < 16; o++) p[o] = 0.f;
    for (int i = blockIdx.x * 256 + t; i < ND4; i += FC_BLOCKS * 256){
        float4 xv = x4[i];
        #pragma unroll
        for (int o = 0; o < 16; o++){
            float4 wv = w4[(size_t)o * ND4 + i];
            p[o] += wv.x * xv.x + wv.y * xv.y + wv.z * xv.z + wv.w * xv.w;
        }
    }
    #pragma unroll
    for (int o = 0; o < 16; o++){
        for (int off = 32; off > 0; off >>= 1) p[o] += __shfl_down(p[o], off, 64);
    }
    __shared__ float red[4][16];
    int lane = t & 63, wid = t >> 6;
    if (lane == 0){
        #pragma unroll
        for (int o = 0; o < 16; o++) red[wid][o] = p[o];
    }
    __syncthreads();
    if (t < 16) partials[blockIdx.x * 16 + t] = red[0][t] + red[1][t] + red[2][t] + red[3][t];
}

__global__ __launch_bounds__(256) void k_fc2(const float* __restrict__ partials, const float* __restrict__ fcb,
                                             float* __restrict__ out){
    __shared__ float red[256];
    int t = threadIdx.x; int o = t & 15, j0 = t >> 4;
    float s = 0.f;
    for (int j = j0; j < FC_BLOCKS; j += 16) s += partials[j * 16 + o];
    red[t] = s; __syncthreads();
    for (int off = 128; off >= 16; off >>= 1){ if (t < off) red[t] += red[t + off]; __syncthreads(); }
    if (t < 16) out[t] = red[t] + fcb[t];
}

extern "C" void kernel_launch(void* const* d_in, const int* in_sizes, int n_in,
                              void* d_out, int out_size, void* d_ws, size_t ws_size,
                              hipStream_t stream) {
    const float* F     = (const float*)d_in[0];
    const int*   src   = (const int*)d_in[1];
    const int*   dst   = (const int*)d_in[2];
    const float* gcn_w = (const float*)d_in[3];
    const float* gcn_b = (const float*)d_in[4];
    const float* fc_w  = (const float*)d_in[5];
    const float* fc_b  = (const float*)d_in[6];
    float* out = (float*)d_out;

    char* wsp = (char*)d_ws;
    auto alloc = [&](size_t bytes) -> char* {
        char* p = wsp;
        wsp += (bytes + 255) & ~size_t(255);
        return p;
    };
    unsigned* deg      = (unsigned*)alloc(2 * Nn * 4);   // deg_out | deg_in, contiguous for one memset
    unsigned* deg_out_ = deg;
    unsigned* deg_in_  = deg + Nn;
    unsigned* offsets  = (unsigned*)alloc((Nn + 1) * 4);
    unsigned* cursor   = (unsigned*)alloc(Nn * 4);
    unsigned* bsum     = (unsigned*)alloc(256 * 4);
    unsigned* boff     = (unsigned*)alloc(256 * 4);
    unsigned* csr      = (unsigned*)alloc(Ee * 4);
    float* norm_src    = (float*)alloc(Nn * 4);
    float* norm_dst    = (float*)alloc(Nn * 4);
    float* partials    = (float*)alloc(FC_BLOCKS * 16 * 4);
    float* h           = (float*)alloc((size_t)Nn * 64 * 4);
    float* agg         = (float*)alloc((size_t)Nn * 64 * 4);
    float* x           = (float*)alloc((size_t)Nn * 64 * 4);

    hipMemsetAsync(deg, 0, 2 * Nn * 4, stream);

    k_degree<<<Ee / 256, 256, 0, stream>>>(src, dst, deg_out_, deg_in_);
    k_norms<<<NBLK, 256, 0, stream>>>(deg_out_, deg_in_, norm_src, norm_dst);
    k_blocksum<<<NBLK, 256, 0, stream>>>(deg_in_, bsum);
    k_scanblocks<<<1, 256, 0, stream>>>(bsum, boff, offsets);
    k_offsets<<<NBLK, 256, 0, stream>>>(deg_in_, boff, offsets, cursor);
    k_fillcsr<<<Ee / 256, 256, 0, stream>>>(src, dst, cursor, csr);

    for (int l = 0; l < 3; l++){
        const float* xin = (l == 0) ? F : x;
        k_h<<<ND4 / 256, 256, 0, stream>>>(xin, norm_src, h);
        k_gather<<<Nn / 4, 256, 0, stream>>>(h, offsets, csr, norm_dst, agg);
        k_gemm<<<(Nn + 63) / 64, 256, 0, stream>>>(agg, gcn_w + (size_t)l * 64 * 64, gcn_b + (size_t)l * 64, x);
    }

    k_fc<<<FC_BLOCKS, 256, 0, stream>>>(fc_w, x, partials);
    k_fc2<<<1, 256, 0, stream>>>(partials, fc_b, out);
}